// Round 3
// baseline (207.469 us; speedup 1.0000x reference)
//
#include <hip/hip_runtime.h>
#include <hip/hip_fp16.h>

// Problem constants
#define B_  8
#define C_  64
#define N_  2000
#define T_  12
#define E_  64000
#define HID_ 32
#define NTILE 16

typedef float f32x4 __attribute__((ext_vector_type(4)));

union H8 {            // 8 halves <-> 16 bytes
  __half2 h[4];
  f32x4   f;
};

// ---------------------------------------------------------------------------
// Kernel 0: fold W3/W4/conv_w/scales into M1/M2 (64x64 each, fp32)
//   M1[c',c] = W1s * sum_{h<32} W3[c',h] * conv_w[c,h]
//   M2[c',c] = W2s * sum_{h<32} W4[c',h] * conv_w[c,32+h]
// ---------------------------------------------------------------------------
__global__ __launch_bounds__(256) void fold_kernel(
    const float* __restrict__ W3, const float* __restrict__ W4,
    const float* __restrict__ conv_w,
    const float* __restrict__ w1s, const float* __restrict__ w2s,
    float* __restrict__ M1, float* __restrict__ M2) {
  int i = blockIdx.x * 256 + threadIdx.x;   // 0..4095
  if (i >= 64 * 64) return;
  int cp = i >> 6;   // c' (row of W3/W4)
  int c  = i & 63;   // output channel (row of conv_w)
  const float* w3 = W3 + cp * HID_;
  const float* w4 = W4 + cp * HID_;
  const float* cw = conv_w + c * (2 * HID_);
  float s1 = 0.f, s2 = 0.f;
#pragma unroll
  for (int h = 0; h < HID_; ++h) {
    s1 += w3[h] * cw[h];
    s2 += w4[h] * cw[HID_ + h];
  }
  M1[i] = s1 * w1s[0];
  M2[i] = s2 * w2s[0];
}

// ---------------------------------------------------------------------------
// Kernel 1: per-node transform -> fp16 A/Bv.
//   lt[b,n,c'] = sum_t x[b,c',n,t] * (t/11)
//   rt[b,n,c'] = S - lt   (t_dn = 1 - t_up)
//   A[b,n,c]  = sum_c' lt * M1[c',c]   (fp16)
//   Bv[b,n,c] = sum_c' rt * M2[c',c]   (fp16)
// Block: 128 threads, one b and NTILE=16 nodes. Grid = 8*125 = 1000.
// Stage 2: thread = (nn = tid>>3, cg = tid&7) owns 8 consecutive channels.
// Each wave reads the full 512 B of M1+M2 rows per cp but serves 8 nodes,
// keeping the loop VALU-bound (32 FMA per 4 global-b128 + 2 ds-b32).
// ---------------------------------------------------------------------------
__global__ __launch_bounds__(128) void node_kernel(
    const float* __restrict__ x,
    const float* __restrict__ M1, const float* __restrict__ M2,
    __half* __restrict__ Ah, __half* __restrict__ Bh) {
  __shared__ float lt[C_ * NTILE];
  __shared__ float rt[C_ * NTILE];

  const int blk = blockIdx.x;
  const int b   = blk / (N_ / NTILE);      // /125
  const int n0  = (blk % (N_ / NTILE)) * NTILE;
  const int tid = threadIdx.x;

  // ---- stage 1: time reduction (64 c' x 16 n = 1024 tasks, 8 per thread)
#pragma unroll
  for (int it = 0; it < (C_ * NTILE) / 128; ++it) {
    int task = it * 128 + tid;
    int cp = task >> 4;        // c'
    int nn = task & 15;        // node within tile
    const float* p = x + ((size_t)(b * C_ + cp) * N_ + (n0 + nn)) * T_;
    f32x4 v0 = *(const f32x4*)(p);
    f32x4 v1 = *(const f32x4*)(p + 4);
    f32x4 v2 = *(const f32x4*)(p + 8);
    float s  = v0[0] + v0[1] + v0[2] + v0[3]
             + v1[0] + v1[1] + v1[2] + v1[3]
             + v2[0] + v2[1] + v2[2] + v2[3];
    float su = (v0[1] * 1.f + v0[2] * 2.f + v0[3] * 3.f
              + v1[0] * 4.f + v1[1] * 5.f + v1[2] * 6.f + v1[3] * 7.f
              + v2[0] * 8.f + v2[1] * 9.f + v2[2] * 10.f + v2[3] * 11.f)
             * (1.0f / 11.0f);
    lt[cp * NTILE + nn] = su;       // t_up weighting
    rt[cp * NTILE + nn] = s - su;   // t_dn = 1 - t_up
  }
  __syncthreads();

  // ---- stage 2: 64-deep dot with M1/M2.
  const int cg = tid & 7;    // 8 consecutive c per thread
  const int nn = tid >> 3;   // node
  float a[8], bb[8];
#pragma unroll
  for (int k = 0; k < 8; ++k) { a[k] = 0.f; bb[k] = 0.f; }
#pragma unroll 8
  for (int cp = 0; cp < C_; ++cp) {
    float lv = lt[cp * NTILE + nn];
    float rv = rt[cp * NTILE + nn];
    f32x4 m1a = *(const f32x4*)(M1 + cp * 64 + cg * 8);
    f32x4 m1b = *(const f32x4*)(M1 + cp * 64 + cg * 8 + 4);
    f32x4 m2a = *(const f32x4*)(M2 + cp * 64 + cg * 8);
    f32x4 m2b = *(const f32x4*)(M2 + cp * 64 + cg * 8 + 4);
#pragma unroll
    for (int k = 0; k < 4; ++k) {
      a[k]      += lv * m1a[k];
      a[4 + k]  += lv * m1b[k];
      bb[k]     += rv * m2a[k];
      bb[4 + k] += rv * m2b[k];
    }
  }
  size_t row = ((size_t)b * N_ + (n0 + nn)) * 64;
  H8 ua, ub;
#pragma unroll
  for (int k = 0; k < 4; ++k) {
    ua.h[k] = __floats2half2_rn(a[2 * k], a[2 * k + 1]);
    ub.h[k] = __floats2half2_rn(bb[2 * k], bb[2 * k + 1]);
  }
  *(f32x4*)(Ah + row + cg * 8) = ua.f;
  *(f32x4*)(Bh + row + cg * 8) = ub.f;
}

// ---------------------------------------------------------------------------
// Kernel 2: edge gather + add.
//   out[b,e,c] = A[b,idx[e],c] + Bv[b,idy[e],c] + conv_b[c]
// 8 threads per (b,e) pair; each reads 16 B from Ah and Bh (one coalesced
// 128 B row per pair per array) and writes 32 B of out nontemporally.
// ---------------------------------------------------------------------------
__global__ __launch_bounds__(256) void gather_kernel(
    const __half* __restrict__ Ah, const __half* __restrict__ Bh,
    const int* __restrict__ idx, const int* __restrict__ idy,
    const float* __restrict__ conv_b, float* __restrict__ out) {
  int g  = blockIdx.x * 256 + threadIdx.x;  // 0 .. B*E*8-1
  int c8 = g & 7;
  int p  = g >> 3;              // (b,e) pair, 0..511999
  int b  = p / E_;
  int e  = p - b * E_;
  int ni = idx[e];
  int nj = idy[e];
  H8 ua = *(const H8*)(Ah + (size_t)(b * N_ + ni) * 64 + c8 * 8);
  H8 ub = *(const H8*)(Bh + (size_t)(b * N_ + nj) * 64 + c8 * 8);
  f32x4 cb0 = *(const f32x4*)(conv_b + c8 * 8);
  f32x4 cb1 = *(const f32x4*)(conv_b + c8 * 8 + 4);
  f32x4 o0, o1;
#pragma unroll
  for (int k = 0; k < 2; ++k) {
    float2 av = __half22float2(ua.h[k]);
    float2 bv = __half22float2(ub.h[k]);
    o0[2 * k]     = av.x + bv.x + cb0[2 * k];
    o0[2 * k + 1] = av.y + bv.y + cb0[2 * k + 1];
    float2 av2 = __half22float2(ua.h[2 + k]);
    float2 bv2 = __half22float2(ub.h[2 + k]);
    o1[2 * k]     = av2.x + bv2.x + cb1[2 * k];
    o1[2 * k + 1] = av2.y + bv2.y + cb1[2 * k + 1];
  }
  float* dst = out + (size_t)p * 64 + c8 * 8;
  __builtin_nontemporal_store(o0, (f32x4*)dst);
  __builtin_nontemporal_store(o1, (f32x4*)(dst + 4));
}

// ---------------------------------------------------------------------------
extern "C" void kernel_launch(void* const* d_in, const int* in_sizes, int n_in,
                              void* d_out, int out_size, void* d_ws, size_t ws_size,
                              hipStream_t stream) {
  const float* x      = (const float*)d_in[0];
  const int*   idx    = (const int*)  d_in[1];
  const int*   idy    = (const int*)  d_in[2];
  const float* w1s    = (const float*)d_in[3];
  const float* w2s    = (const float*)d_in[4];
  const float* W3     = (const float*)d_in[5];
  const float* W4     = (const float*)d_in[6];
  const float* conv_w = (const float*)d_in[7];
  const float* conv_b = (const float*)d_in[8];
  float* out = (float*)d_out;

  float*  W  = (float*)d_ws;
  float*  M1 = W;                         // 4096 floats
  float*  M2 = W + 4096;                  // 4096 floats
  __half* Ah = (__half*)(W + 8192);       // B*N*64 halves = 2 MB
  __half* Bh = Ah + (size_t)B_ * N_ * 64;

  fold_kernel<<<16, 256, 0, stream>>>(W3, W4, conv_w, w1s, w2s, M1, M2);
  node_kernel<<<B_ * (N_ / NTILE), 128, 0, stream>>>(x, M1, M2, Ah, Bh);
  gather_kernel<<<(B_ * E_ * 8) / 256, 256, 0, stream>>>(Ah, Bh, idx, idy, conv_b, out);
}